// Round 2
// baseline (328.399 us; speedup 1.0000x reference)
//
#include <hip/hip_runtime.h>

typedef __attribute__((ext_vector_type(8))) short bf16x8;
typedef __attribute__((ext_vector_type(4))) float f32x4;
typedef __attribute__((ext_vector_type(4))) unsigned short us4;

#define AS1 __attribute__((address_space(1)))
#define AS3 __attribute__((address_space(3)))

__device__ __forceinline__ unsigned short f2bf(float f) {
  unsigned u = __float_as_uint(f);
  u += 0x7fff + ((u >> 16) & 1);   // RNE
  return (unsigned short)(u >> 16);
}

__device__ __forceinline__ void gload_lds16(const void* g, void* l) {
  __builtin_amdgcn_global_load_lds((const AS1 unsigned int*)g,
                                   (AS3 unsigned int*)l, 16, 0, 0);
}

#define MFMA16(a, b, c) __builtin_amdgcn_mfma_f32_16x16x32_bf16(a, b, c, 0, 0, 0)

// ---------------------------------------------------------------------------
// 8-phase 256x256 BK=64 bf16 GEMM (T2 swizzle + T3/T4 counted vmcnt + T5
// setprio). C[M,N] = scale*(A[M,K] @ Bt[N,K]^T) + bias.
// 512 thr = 8 waves (2M x 4N), per-wave 128x64 of 16x16x32 MFMA.
// LDS: 2 buf x (A[256][64] + B[256][64]) bf16 = 128 KiB, linear rows,
// chunk-XOR swizzle (chunk ^= row&7) applied on the PRE-SWIZZLED global
// source (global_load_lds dest must be linear) and on the ds_read side.
// B LDS rows are permuted: ldsrow = nh*128 + wn*32 + (grow&31), where
// grow = wn*64 + nh*32 + low5, so stage units (64 rows) match phase
// consumption deadlines.
// Stage order per tile: phA: A0,A128 | phB: B0,B64 | phC: B128,B192 |
// phD: A64,A192.  Waits: vmcnt(4) at end of phases A, B, D (never 0 in
// loop). Deadline proof: at each wait, outstanding = 6..8 and the needed
// unit is exactly the oldest (outstanding-4); a barrier after each wait
// publishes the landing to all waves (each wave stages a slice of every
// unit in identical order, so per-wave vmcnt + barrier => unit complete).
// MODE 0: C[bz*sC + row*ldc + col]. MODE 1 (fused QKV): per-256-col tile,
// piece = gcol>>10; pieces 0,1 -> compact [8192][1024] at C + piece*sC;
// piece 2 -> V transposed to Vt[b][d][2048], b = row>>11.
// ---------------------------------------------------------------------------
template <typename OutT, bool BIAS, int MODE>
__global__ __launch_bounds__(512, 2) void gemm8p(
    const unsigned short* __restrict__ A,
    const unsigned short* __restrict__ Bt,
    OutT* __restrict__ C,
    unsigned short* __restrict__ Vt,
    const float* __restrict__ bias,
    int Kd, int lda, int ldb, int ldc,
    long sA, long sB, long sC,
    float scale) {
  constexpr int BOFF = 256 * 64;           // B offset in ushorts within a buffer
  __shared__ unsigned short lds[2][512 * 64];   // 128 KiB

  const int bz = blockIdx.z;
  A  += (size_t)bz * sA + (size_t)blockIdx.x * 256 * lda;
  Bt += (size_t)bz * sB + (size_t)blockIdx.y * 256 * ldb;

  const int tid  = threadIdx.x;
  const int wave = tid >> 6;
  const int lane = tid & 63;
  const int wm   = wave >> 2;              // 0..1
  const int wn   = wave & 3;               // 0..3
  const int l15  = lane & 15;
  const int hi   = lane >> 4;              // 0..3
  // stage-side: thread covers LDS (row = r0 + sr, chunk = sc8) of a 64-row unit
  const int sr  = (wave << 3) + (lane >> 3);   // 0..63
  const int sc8 = lane & 7;
  // read-side swizzled chunk byte offsets (ushort units), row&7 == lane&7
  const int co0 = ((hi    ) ^ (lane & 7)) << 3;
  const int co1 = ((hi + 4) ^ (lane & 7)) << 3;
  const int rA0 = wm * 128 + l15;          // + mt*16 (+64 for mh=1)
  const int rB0 = wn * 32 + l15;           // + nh*128 + ntl*16 (permuted rows)

  auto stA = [&](int b, int k0, int r0) {
    const unsigned short* g =
        A + (size_t)(r0 + sr) * lda + (k0 + ((sc8 ^ (sr & 7)) << 3));
    gload_lds16(g, &lds[b][(r0 + (wave << 3)) * 64]);
  };
  auto stB = [&](int b, int k0, int r0) {
    const int lr = r0 + sr;                                    // LDS row
    const int gr = ((lr >> 5) & 3) * 64 + ((lr >> 7) << 5) + (lr & 31);
    const unsigned short* g =
        Bt + (size_t)gr * ldb + (k0 + ((sc8 ^ (lr & 7)) << 3));
    gload_lds16(g, &lds[b][BOFF + (r0 + (wave << 3)) * 64]);
  };

  f32x4 acc[8][4] = {};
  bf16x8 af[4][2], b0f[2][2], b1f[2][2];

  // prologue: stage tile 0 in steady-state order, keep last 4 in flight
  stA(0, 0, 0);   stA(0, 0, 128);
  stB(0, 0, 0);   stB(0, 0, 64);
  stB(0, 0, 128); stB(0, 0, 192);
  stA(0, 0, 64);  stA(0, 0, 192);
  asm volatile("s_waitcnt vmcnt(4)" ::: "memory");
  __builtin_amdgcn_s_barrier();

  const int NT = Kd >> 6;
  for (int t = 0; t < NT; ++t) {
    const int buf = t & 1;
    const int nb  = buf ^ 1;
    const int nk0 = (t + 1) << 6;
    const bool st = (t + 1) < NT;
    const unsigned short* Lr = &lds[buf][0];

    // ---------------- phase A: quadrant (mh0, nh0) ----------------
#pragma unroll
    for (int mt = 0; mt < 4; ++mt) {
      af[mt][0] = *(const bf16x8*)&Lr[(rA0 + mt * 16) * 64 + co0];
      af[mt][1] = *(const bf16x8*)&Lr[(rA0 + mt * 16) * 64 + co1];
    }
#pragma unroll
    for (int n = 0; n < 2; ++n) {
      b0f[n][0] = *(const bf16x8*)&Lr[BOFF + (rB0 + n * 16) * 64 + co0];
      b0f[n][1] = *(const bf16x8*)&Lr[BOFF + (rB0 + n * 16) * 64 + co1];
    }
    if (st) { stA(nb, nk0, 0); stA(nb, nk0, 128); }
    __builtin_amdgcn_s_barrier();
    __builtin_amdgcn_s_setprio(1);
#pragma unroll
    for (int mt = 0; mt < 4; ++mt)
#pragma unroll
      for (int n = 0; n < 2; ++n) {
        acc[mt][n] = MFMA16(af[mt][0], b0f[n][0], acc[mt][n]);
        acc[mt][n] = MFMA16(af[mt][1], b0f[n][1], acc[mt][n]);
      }
    __builtin_amdgcn_s_setprio(0);
    asm volatile("s_waitcnt vmcnt(4)" ::: "memory");   // B128,B192 landed
    __builtin_amdgcn_s_barrier();

    // ---------------- phase B: quadrant (mh0, nh1) ----------------
#pragma unroll
    for (int n = 0; n < 2; ++n) {
      b1f[n][0] = *(const bf16x8*)&Lr[BOFF + (128 + rB0 + n * 16) * 64 + co0];
      b1f[n][1] = *(const bf16x8*)&Lr[BOFF + (128 + rB0 + n * 16) * 64 + co1];
    }
    if (st) { stB(nb, nk0, 0); stB(nb, nk0, 64); }
    __builtin_amdgcn_s_barrier();
    __builtin_amdgcn_s_setprio(1);
#pragma unroll
    for (int mt = 0; mt < 4; ++mt)
#pragma unroll
      for (int n = 0; n < 2; ++n) {
        acc[mt][2 + n] = MFMA16(af[mt][0], b1f[n][0], acc[mt][2 + n]);
        acc[mt][2 + n] = MFMA16(af[mt][1], b1f[n][1], acc[mt][2 + n]);
      }
    __builtin_amdgcn_s_setprio(0);
    asm volatile("s_waitcnt vmcnt(4)" ::: "memory");   // A64,A192 landed
    __builtin_amdgcn_s_barrier();

    // ---------------- phase C: quadrant (mh1, nh1) ----------------
#pragma unroll
    for (int mt = 0; mt < 4; ++mt) {
      af[mt][0] = *(const bf16x8*)&Lr[(64 + rA0 + mt * 16) * 64 + co0];
      af[mt][1] = *(const bf16x8*)&Lr[(64 + rA0 + mt * 16) * 64 + co1];
    }
    if (st) { stB(nb, nk0, 128); stB(nb, nk0, 192); }
    __builtin_amdgcn_s_barrier();
    __builtin_amdgcn_s_setprio(1);
#pragma unroll
    for (int mt = 0; mt < 4; ++mt)
#pragma unroll
      for (int n = 0; n < 2; ++n) {
        acc[4 + mt][2 + n] = MFMA16(af[mt][0], b1f[n][0], acc[4 + mt][2 + n]);
        acc[4 + mt][2 + n] = MFMA16(af[mt][1], b1f[n][1], acc[4 + mt][2 + n]);
      }
    __builtin_amdgcn_s_setprio(0);
    __builtin_amdgcn_s_barrier();                      // no vmcnt here

    // ---------------- phase D: quadrant (mh1, nh0) ----------------
    if (st) { stA(nb, nk0, 64); stA(nb, nk0, 192); }
    __builtin_amdgcn_s_barrier();
    __builtin_amdgcn_s_setprio(1);
#pragma unroll
    for (int mt = 0; mt < 4; ++mt)
#pragma unroll
      for (int n = 0; n < 2; ++n) {
        acc[4 + mt][n] = MFMA16(af[mt][0], b0f[n][0], acc[4 + mt][n]);
        acc[4 + mt][n] = MFMA16(af[mt][1], b0f[n][1], acc[4 + mt][n]);
      }
    __builtin_amdgcn_s_setprio(0);
    asm volatile("s_waitcnt vmcnt(4)" ::: "memory");   // next A0,A128,B0,B64
    __builtin_amdgcn_s_barrier();
  }

  // ------------------------------- epilogue -------------------------------
  const int hi4  = hi << 2;
  const int row0 = blockIdx.x * 256 + wm * 128;
  const int col0 = blockIdx.y * 256 + wn * 64;

  if constexpr (MODE == 1) {
#pragma unroll
    for (int nt = 0; nt < 4; ++nt) {
      const int gcol  = col0 + nt * 16;
      const int piece = gcol >> 10;
      const float bv  = BIAS ? bias[gcol + l15] : 0.0f;
      if (piece < 2) {
        OutT* dst = C + (size_t)piece * sC;
        const int col = (gcol & 1023) + l15;
#pragma unroll
        for (int mt = 0; mt < 8; ++mt)
#pragma unroll
          for (int r = 0; r < 4; ++r) {
            const int row = row0 + mt * 16 + hi4 + r;
            dst[(size_t)row * ldc + col] = (OutT)f2bf(acc[mt][nt][r] * scale + bv);
          }
      } else {
        // V piece: write transposed Vt[b][d][2048]
        const int d = (gcol & 1023) + l15;
        const int b = blockIdx.x >> 3;
        const int sb = (blockIdx.x & 7) * 256 + wm * 128 + hi4;
#pragma unroll
        for (int mt = 0; mt < 8; ++mt) {
          us4 pk;
          pk.x = f2bf(acc[mt][nt][0] * scale + bv);
          pk.y = f2bf(acc[mt][nt][1] * scale + bv);
          pk.z = f2bf(acc[mt][nt][2] * scale + bv);
          pk.w = f2bf(acc[mt][nt][3] * scale + bv);
          *(us4*)&Vt[((size_t)b << 21) + (size_t)d * 2048 + sb + mt * 16] = pk;
        }
      }
    }
  } else {
    C += (size_t)bz * sC;
#pragma unroll
    for (int nt = 0; nt < 4; ++nt) {
      const int col = col0 + nt * 16 + l15;
      const float bv = BIAS ? bias[col] : 0.0f;
#pragma unroll
      for (int mt = 0; mt < 8; ++mt)
#pragma unroll
        for (int r = 0; r < 4; ++r) {
          const int row = row0 + mt * 16 + hi4 + r;
          const float v = acc[mt][nt][r] * scale + bv;
          if constexpr (sizeof(OutT) == 4)
            C[(size_t)row * ldc + col] = v;
          else
            C[(size_t)row * ldc + col] = (OutT)f2bf(v);
        }
    }
  }
}

// fp32 -> bf16 flat convert (4 elems/thread)
__global__ void cvt_x(const float* __restrict__ in, unsigned short* __restrict__ out, int n4) {
  const int i = blockIdx.x * blockDim.x + threadIdx.x;
  if (i < n4) {
    const float4 v = ((const float4*)in)[i];
    uint2 o;
    o.x = (unsigned)f2bf(v.x) | ((unsigned)f2bf(v.y) << 16);
    o.y = (unsigned)f2bf(v.z) | ((unsigned)f2bf(v.w) << 16);
    ((uint2*)out)[i] = o;
  }
}

// All 4 weight matrices (1024x1024 fp32) -> bf16 transposed, one launch.
__global__ void cvtT_w4(const float* __restrict__ Wq, const float* __restrict__ Wk,
                        const float* __restrict__ Wv, const float* __restrict__ Wo,
                        unsigned short* __restrict__ Wqkvb, unsigned short* __restrict__ Wob) {
  __shared__ unsigned short tile[64][65];
  const int z = blockIdx.z;
  const float* in = (z == 0) ? Wq : (z == 1) ? Wk : (z == 2) ? Wv : Wo;
  unsigned short* out = (z == 3) ? Wob : Wqkvb + (size_t)z * 1024 * 1024;
  const int r0 = blockIdx.y * 64, c0 = blockIdx.x * 64;
  for (int i = threadIdx.y; i < 64; i += 4)
    tile[i][threadIdx.x] = f2bf(in[(size_t)(r0 + i) * 1024 + c0 + threadIdx.x]);
  __syncthreads();
  for (int i = threadIdx.y; i < 64; i += 4)
    out[(size_t)(c0 + i) * 1024 + r0 + threadIdx.x] = tile[threadIdx.x][i];
}

// concat bq|bk|bv into bqkv
__global__ void concat_bias(const float* __restrict__ bq, const float* __restrict__ bk,
                            const float* __restrict__ bv, float* __restrict__ dst) {
  const int z = blockIdx.x;
  const float* src = (z == 0) ? bq : (z == 1) ? bk : bv;
  const int i = threadIdx.x;
  ((float4*)(dst + z * 1024))[i] = ((const float4*)src)[i];
}

// One block per row of 2048 bf16 scores; softmax in fp32, bf16 in place.
__global__ __launch_bounds__(256) void softmax_bf16(unsigned short* __restrict__ scores) {
  unsigned short* p = scores + (size_t)blockIdx.x * 2048;
  const int t = threadIdx.x;
  uint4 raw = ((const uint4*)p)[t];
  float v[8];
  v[0] = __uint_as_float(raw.x << 16); v[1] = __uint_as_float(raw.x & 0xffff0000u);
  v[2] = __uint_as_float(raw.y << 16); v[3] = __uint_as_float(raw.y & 0xffff0000u);
  v[4] = __uint_as_float(raw.z << 16); v[5] = __uint_as_float(raw.z & 0xffff0000u);
  v[6] = __uint_as_float(raw.w << 16); v[7] = __uint_as_float(raw.w & 0xffff0000u);

  float m = v[0];
#pragma unroll
  for (int i = 1; i < 8; ++i) m = fmaxf(m, v[i]);
#pragma unroll
  for (int off = 32; off; off >>= 1) m = fmaxf(m, __shfl_xor(m, off, 64));

  __shared__ float red[4];
  __shared__ float bcast[2];
  const int wave = t >> 6, lane = t & 63;
  if (lane == 0) red[wave] = m;
  __syncthreads();
  if (t == 0) bcast[0] = fmaxf(fmaxf(red[0], red[1]), fmaxf(red[2], red[3]));
  __syncthreads();
  m = bcast[0];

  float s = 0.f;
#pragma unroll
  for (int i = 0; i < 8; ++i) { v[i] = __expf(v[i] - m); s += v[i]; }
#pragma unroll
  for (int off = 32; off; off >>= 1) s += __shfl_xor(s, off, 64);
  if (lane == 0) red[wave] = s;
  __syncthreads();
  if (t == 0) bcast[1] = red[0] + red[1] + red[2] + red[3];
  __syncthreads();
  const float inv = 1.0f / bcast[1];

  uint4 ov;
  ov.x = (unsigned)f2bf(v[0] * inv) | ((unsigned)f2bf(v[1] * inv) << 16);
  ov.y = (unsigned)f2bf(v[2] * inv) | ((unsigned)f2bf(v[3] * inv) << 16);
  ov.z = (unsigned)f2bf(v[4] * inv) | ((unsigned)f2bf(v[5] * inv) << 16);
  ov.w = (unsigned)f2bf(v[6] * inv) | ((unsigned)f2bf(v[7] * inv) << 16);
  ((uint4*)p)[t] = ov;
}

// ---------------------------------------------------------------------------
extern "C" void kernel_launch(void* const* d_in, const int* in_sizes, int n_in,
                              void* d_out, int out_size, void* d_ws, size_t ws_size,
                              hipStream_t stream) {
  const float* x  = (const float*)d_in[0];
  const float* Wq = (const float*)d_in[1];
  const float* bq = (const float*)d_in[2];
  const float* Wk = (const float*)d_in[3];
  const float* bk = (const float*)d_in[4];
  const float* Wv = (const float*)d_in[5];
  const float* bv = (const float*)d_in[6];
  const float* Wo = (const float*)d_in[7];
  const float* bo = (const float*)d_in[8];
  float* out = (float*)d_out;

  char* ws = (char*)d_ws;
  size_t off = 0;
  auto alloc = [&](size_t bytes) { char* p = ws + off; off += (bytes + 255) & ~255UL; return p; };
  unsigned short* xb    = (unsigned short*)alloc(8192UL * 1024 * 2);     // 16 MiB
  unsigned short* Wqkvb = (unsigned short*)alloc(3072UL * 1024 * 2);     // 6 MiB
  unsigned short* Wob   = (unsigned short*)alloc(1024UL * 1024 * 2);     // 2 MiB
  float*          bqkv  = (float*)alloc(3072UL * 4);
  unsigned short* Qb    = (unsigned short*)alloc(8192UL * 1024 * 2);     // 16 MiB (piece 0)
  unsigned short* Kb    = (unsigned short*)alloc(8192UL * 1024 * 2);     // 16 MiB (piece 1, == Qb + sC)
  unsigned short* Vtb   = (unsigned short*)alloc(4UL * 1024 * 2048 * 2); // 16 MiB [b][d][s]
  unsigned short* attn  = (unsigned short*)alloc(8192UL * 2048 * 2);     // 32 MiB bf16 scores
  unsigned short* ctxb  = (unsigned short*)alloc(8192UL * 1024 * 2);     // 16 MiB

  const dim3 blk(512);

  // input convert + all weight transposes + bias concat
  cvt_x<<<2097152 / 256, 256, 0, stream>>>(x, xb, 2097152);
  cvtT_w4<<<dim3(16, 16, 4), dim3(64, 4), 0, stream>>>(Wq, Wk, Wv, Wo, Wqkvb, Wob);
  concat_bias<<<3, 256, 0, stream>>>(bq, bk, bv, bqkv);

  // fused QKV projection: Q,K compact + V transposed to Vtb.
  gemm8p<unsigned short, true, 1><<<dim3(32, 12, 1), blk, 0, stream>>>(
      xb, Wqkvb, Qb, Vtb, bqkv, 1024, 1024, 1024, 1024, 0, 0, 8192L * 1024, 1.0f);

  // scores = (Q @ K^T) / 32 -> bf16, per batch
  gemm8p<unsigned short, false, 0><<<dim3(8, 8, 4), blk, 0, stream>>>(
      Qb, Kb, attn, nullptr, nullptr, 1024, 1024, 1024, 2048,
      2048L * 1024, 2048L * 1024, 2048L * 2048, 0.03125f);

  // softmax rows in place (bf16, dense ld=2048)
  softmax_bf16<<<8192, 256, 0, stream>>>(attn);

  // ctx = attn @ V  (attn lda=2048, Vt is Bt layout)
  gemm8p<unsigned short, false, 0><<<dim3(8, 4, 4), blk, 0, stream>>>(
      attn, Vtb, ctxb, nullptr, nullptr, 2048, 2048, 2048, 1024,
      2048L * 2048, 1024L * 2048, 2048L * 1024, 1.0f);

  // out = ctx @ Wo + bo (fp32 out)
  gemm8p<float, true, 0><<<dim3(32, 4, 1), blk, 0, stream>>>(
      ctxb, Wob, out, nullptr, bo, 1024, 1024, 1024, 1024, 0, 0, 0, 1.0f);
}

// Round 3
// 323.372 us; speedup vs baseline: 1.0155x; 1.0155x over previous
//
#include <hip/hip_runtime.h>

typedef __attribute__((ext_vector_type(8))) short bf16x8;
typedef __attribute__((ext_vector_type(4))) float f32x4;
typedef __attribute__((ext_vector_type(4))) unsigned short us4;

#define AS1 __attribute__((address_space(1)))
#define AS3 __attribute__((address_space(3)))

__device__ __forceinline__ unsigned short f2bf(float f) {
  unsigned u = __float_as_uint(f);
  u += 0x7fff + ((u >> 16) & 1);   // RNE
  return (unsigned short)(u >> 16);
}

__device__ __forceinline__ void gload_lds16(const void* g, void* l) {
  __builtin_amdgcn_global_load_lds((const AS1 unsigned int*)g,
                                   (AS3 unsigned int*)l, 16, 0, 0);
}

#define MFMA16(a, b, c) __builtin_amdgcn_mfma_f32_16x16x32_bf16(a, b, c, 0, 0, 0)

// ---------------------------------------------------------------------------
// 8-phase 256x256 BK=64 bf16 GEMM. C[M,N] = scale*(A[M,K] @ Bt[N,K]^T) + bias.
// 512 thr = 8 waves (2M x 4N), per-wave 128x64 of 16x16x32 MFMA.
// LDS: 2 buf x (A[256][64] + B[256][64]) bf16 = 128 KiB, linear rows,
// chunk-XOR swizzle (chunk ^= row&7), pre-swizzled global source.
// B LDS rows permuted (ldsrow = nh*128 + wn*32 + low5) so stage units match
// phase deadlines.
//
// Deep-pipeline stage schedule (round-3 fix; 3-phase deadlines, 2 waits/tile):
//   phase A: issue first group of t+1  (A0,A128,B0,B64)    [4 loads]
//   phase B: issue second group of t+1 (B128,B192,A64,A192)[4 loads]
//   end-of-A: vmcnt(4) -> drains SECOND group of tile t (issued B(t-1));
//             read by phases B (B128,B192) and C (A64,A192). 3-phase deadline.
//   end-of-D: vmcnt(4) -> drains FIRST group of tile t+1 (issued A(t));
//             read by phase A(t+1). 3-phase deadline.
//   Outstanding: 8 peak, 4 at iteration boundaries; never drained to 0 in
//   steady state. Last iter (no issues): end-of-A uses vmcnt(0) since only
//   4 outstanding (vmcnt(4) would be a no-op and phase B would race).
// MODE 0: C[bz*sC + row*ldc + col]. MODE 1 (fused QKV): piece = col0>>10
//   (wave-uniform: 64-col wave span never crosses a 1024 boundary);
//   pieces 0,1 -> compact [8192][1024] at C + piece*sC; piece 2 -> V
//   transposed to Vt[b][d][2048], b = blockIdx.x>>3.
// ---------------------------------------------------------------------------
template <typename OutT, bool BIAS, int MODE>
__global__ __launch_bounds__(512, 2) void gemm8p(
    const unsigned short* __restrict__ A,
    const unsigned short* __restrict__ Bt,
    OutT* __restrict__ C,
    unsigned short* __restrict__ Vt,
    const float* __restrict__ bias,
    int Kd, int lda, int ldb, int ldc,
    long sA, long sB, long sC,
    float scale) {
  constexpr int BOFF = 256 * 64;           // B offset in ushorts within a buffer
  __shared__ unsigned short lds[2][512 * 64];   // 128 KiB

  const int bz = blockIdx.z;
  A  += (size_t)bz * sA + (size_t)blockIdx.x * 256 * lda;
  Bt += (size_t)bz * sB + (size_t)blockIdx.y * 256 * ldb;

  const int tid  = threadIdx.x;
  const int wave = tid >> 6;
  const int lane = tid & 63;
  const int wm   = wave >> 2;              // 0..1
  const int wn   = wave & 3;               // 0..3
  const int l15  = lane & 15;
  const int hi   = lane >> 4;              // 0..3
  // stage-side: thread covers LDS (row = r0 + sr, chunk = sc8) of a 64-row unit
  const int sr  = (wave << 3) + (lane >> 3);   // 0..63
  const int sc8 = lane & 7;
  // read-side swizzled chunk byte offsets (ushort units), row&7 == lane&7
  const int co0 = ((hi    ) ^ (lane & 7)) << 3;
  const int co1 = ((hi + 4) ^ (lane & 7)) << 3;
  const int rA0 = wm * 128 + l15;          // + mt*16 (+64 for mh=1)
  const int rB0 = wn * 32 + l15;           // + nh*128 + ntl*16 (permuted rows)

  auto stA = [&](int b, int k0, int r0) {
    const unsigned short* g =
        A + (size_t)(r0 + sr) * lda + (k0 + ((sc8 ^ (sr & 7)) << 3));
    gload_lds16(g, &lds[b][(r0 + (wave << 3)) * 64]);
  };
  auto stB = [&](int b, int k0, int r0) {
    const int lr = r0 + sr;                                    // LDS row
    const int gr = ((lr >> 5) & 3) * 64 + ((lr >> 7) << 5) + (lr & 31);
    const unsigned short* g =
        Bt + (size_t)gr * ldb + (k0 + ((sc8 ^ (lr & 7)) << 3));
    gload_lds16(g, &lds[b][BOFF + (r0 + (wave << 3)) * 64]);
  };

  f32x4 acc[8][4] = {};
  bf16x8 af[4][2], b0f[2][2], b1f[2][2];

  // prologue: stage tile 0 in steady-state issue order (first group, second
  // group); drain first group, keep second group (4) in flight.
  stA(0, 0, 0);   stA(0, 0, 128);
  stB(0, 0, 0);   stB(0, 0, 64);
  stB(0, 0, 128); stB(0, 0, 192);
  stA(0, 0, 64);  stA(0, 0, 192);
  asm volatile("s_waitcnt vmcnt(4)" ::: "memory");
  __builtin_amdgcn_s_barrier();

  const int NT = Kd >> 6;
  for (int t = 0; t < NT; ++t) {
    const int buf = t & 1;
    const int nb  = buf ^ 1;
    const int nk0 = (t + 1) << 6;
    const bool st = (t + 1) < NT;
    const unsigned short* Lr = &lds[buf][0];

    // ---------------- phase A: quadrant (mh0, nh0) ----------------
#pragma unroll
    for (int mt = 0; mt < 4; ++mt) {
      af[mt][0] = *(const bf16x8*)&Lr[(rA0 + mt * 16) * 64 + co0];
      af[mt][1] = *(const bf16x8*)&Lr[(rA0 + mt * 16) * 64 + co1];
    }
#pragma unroll
    for (int n = 0; n < 2; ++n) {
      b0f[n][0] = *(const bf16x8*)&Lr[BOFF + (rB0 + n * 16) * 64 + co0];
      b0f[n][1] = *(const bf16x8*)&Lr[BOFF + (rB0 + n * 16) * 64 + co1];
    }
    if (st) { stA(nb, nk0, 0); stA(nb, nk0, 128); stB(nb, nk0, 0); stB(nb, nk0, 64); }
    __builtin_amdgcn_s_barrier();
    __builtin_amdgcn_s_setprio(1);
#pragma unroll
    for (int mt = 0; mt < 4; ++mt)
#pragma unroll
      for (int n = 0; n < 2; ++n) {
        acc[mt][n] = MFMA16(af[mt][0], b0f[n][0], acc[mt][n]);
        acc[mt][n] = MFMA16(af[mt][1], b0f[n][1], acc[mt][n]);
      }
    __builtin_amdgcn_s_setprio(0);
    if (st) asm volatile("s_waitcnt vmcnt(4)" ::: "memory");   // 2nd group of t
    else    asm volatile("s_waitcnt vmcnt(0)" ::: "memory");   // last iter
    __builtin_amdgcn_s_barrier();

    // ---------------- phase B: quadrant (mh0, nh1) ----------------
#pragma unroll
    for (int n = 0; n < 2; ++n) {
      b1f[n][0] = *(const bf16x8*)&Lr[BOFF + (128 + rB0 + n * 16) * 64 + co0];
      b1f[n][1] = *(const bf16x8*)&Lr[BOFF + (128 + rB0 + n * 16) * 64 + co1];
    }
    if (st) { stB(nb, nk0, 128); stB(nb, nk0, 192); stA(nb, nk0, 64); stA(nb, nk0, 192); }
    __builtin_amdgcn_s_barrier();
    __builtin_amdgcn_s_setprio(1);
#pragma unroll
    for (int mt = 0; mt < 4; ++mt)
#pragma unroll
      for (int n = 0; n < 2; ++n) {
        acc[mt][2 + n] = MFMA16(af[mt][0], b1f[n][0], acc[mt][2 + n]);
        acc[mt][2 + n] = MFMA16(af[mt][1], b1f[n][1], acc[mt][2 + n]);
      }
    __builtin_amdgcn_s_setprio(0);
    __builtin_amdgcn_s_barrier();                      // no wait

    // ---------------- phase C: quadrant (mh1, nh1) ----------------
#pragma unroll
    for (int mt = 0; mt < 4; ++mt) {
      af[mt][0] = *(const bf16x8*)&Lr[(64 + rA0 + mt * 16) * 64 + co0];
      af[mt][1] = *(const bf16x8*)&Lr[(64 + rA0 + mt * 16) * 64 + co1];
    }
    __builtin_amdgcn_s_barrier();
    __builtin_amdgcn_s_setprio(1);
#pragma unroll
    for (int mt = 0; mt < 4; ++mt)
#pragma unroll
      for (int n = 0; n < 2; ++n) {
        acc[4 + mt][2 + n] = MFMA16(af[mt][0], b1f[n][0], acc[4 + mt][2 + n]);
        acc[4 + mt][2 + n] = MFMA16(af[mt][1], b1f[n][1], acc[4 + mt][2 + n]);
      }
    __builtin_amdgcn_s_setprio(0);
    __builtin_amdgcn_s_barrier();                      // no wait

    // ---------------- phase D: quadrant (mh1, nh0) ----------------
    __builtin_amdgcn_s_barrier();
    __builtin_amdgcn_s_setprio(1);
#pragma unroll
    for (int mt = 0; mt < 4; ++mt)
#pragma unroll
      for (int n = 0; n < 2; ++n) {
        acc[4 + mt][n] = MFMA16(af[mt][0], b0f[n][0], acc[4 + mt][n]);
        acc[4 + mt][n] = MFMA16(af[mt][1], b0f[n][1], acc[4 + mt][n]);
      }
    __builtin_amdgcn_s_setprio(0);
    if (st) asm volatile("s_waitcnt vmcnt(4)" ::: "memory");   // 1st group of t+1
    __builtin_amdgcn_s_barrier();
  }

  // ------------------------------- epilogue -------------------------------
  const int hi4  = hi << 2;
  const int row0 = blockIdx.x * 256 + wm * 128;
  const int col0 = blockIdx.y * 256 + wn * 64;

  if constexpr (MODE == 1) {
    const int piece = col0 >> 10;                 // wave-uniform
    float bvv[4];
#pragma unroll
    for (int nt = 0; nt < 4; ++nt)
      bvv[nt] = BIAS ? bias[col0 + nt * 16 + l15] : 0.0f;
    if (piece < 2) {
      OutT* dst = C + (size_t)piece * sC;
      const int cb = (col0 & 1023) + l15;
#pragma unroll
      for (int mt = 0; mt < 8; ++mt)
#pragma unroll
        for (int r = 0; r < 4; ++r) {
          const size_t rowoff = (size_t)(row0 + mt * 16 + hi4 + r) * ldc;
#pragma unroll
          for (int nt = 0; nt < 4; ++nt)
            dst[rowoff + cb + nt * 16] = (OutT)f2bf(acc[mt][nt][r] * scale + bvv[nt]);
        }
    } else {
      // V piece: write transposed Vt[b][d][2048]
      const int b = blockIdx.x >> 3;
      const int sb = (blockIdx.x & 7) * 256 + wm * 128 + hi4;
#pragma unroll
      for (int nt = 0; nt < 4; ++nt) {
        const int d = ((col0 + nt * 16) & 1023) + l15;
#pragma unroll
        for (int mt = 0; mt < 8; ++mt) {
          us4 pk;
          pk.x = f2bf(acc[mt][nt][0] * scale + bvv[nt]);
          pk.y = f2bf(acc[mt][nt][1] * scale + bvv[nt]);
          pk.z = f2bf(acc[mt][nt][2] * scale + bvv[nt]);
          pk.w = f2bf(acc[mt][nt][3] * scale + bvv[nt]);
          *(us4*)&Vt[((size_t)b << 21) + (size_t)d * 2048 + sb + mt * 16] = pk;
        }
      }
    }
  } else {
    C += (size_t)bz * sC;
    float bvv[4];
#pragma unroll
    for (int nt = 0; nt < 4; ++nt)
      bvv[nt] = BIAS ? bias[col0 + nt * 16 + l15] : 0.0f;
    const int cb = col0 + l15;
#pragma unroll
    for (int mt = 0; mt < 8; ++mt)
#pragma unroll
      for (int r = 0; r < 4; ++r) {
        const size_t rowoff = (size_t)(row0 + mt * 16 + hi4 + r) * ldc;
#pragma unroll
        for (int nt = 0; nt < 4; ++nt) {
          const float v = acc[mt][nt][r] * scale + bvv[nt];
          if constexpr (sizeof(OutT) == 4)
            C[rowoff + cb + nt * 16] = v;
          else
            C[rowoff + cb + nt * 16] = (OutT)f2bf(v);
        }
      }
  }
}

// fp32 -> bf16 flat convert (4 elems/thread)
__global__ void cvt_x(const float* __restrict__ in, unsigned short* __restrict__ out, int n4) {
  const int i = blockIdx.x * blockDim.x + threadIdx.x;
  if (i < n4) {
    const float4 v = ((const float4*)in)[i];
    uint2 o;
    o.x = (unsigned)f2bf(v.x) | ((unsigned)f2bf(v.y) << 16);
    o.y = (unsigned)f2bf(v.z) | ((unsigned)f2bf(v.w) << 16);
    ((uint2*)out)[i] = o;
  }
}

// All 4 weight matrices (1024x1024 fp32) -> bf16 transposed, one launch.
__global__ void cvtT_w4(const float* __restrict__ Wq, const float* __restrict__ Wk,
                        const float* __restrict__ Wv, const float* __restrict__ Wo,
                        unsigned short* __restrict__ Wqkvb, unsigned short* __restrict__ Wob) {
  __shared__ unsigned short tile[64][65];
  const int z = blockIdx.z;
  const float* in = (z == 0) ? Wq : (z == 1) ? Wk : (z == 2) ? Wv : Wo;
  unsigned short* out = (z == 3) ? Wob : Wqkvb + (size_t)z * 1024 * 1024;
  const int r0 = blockIdx.y * 64, c0 = blockIdx.x * 64;
  for (int i = threadIdx.y; i < 64; i += 4)
    tile[i][threadIdx.x] = f2bf(in[(size_t)(r0 + i) * 1024 + c0 + threadIdx.x]);
  __syncthreads();
  for (int i = threadIdx.y; i < 64; i += 4)
    out[(size_t)(c0 + i) * 1024 + r0 + threadIdx.x] = tile[threadIdx.x][i];
}

// concat bq|bk|bv into bqkv
__global__ void concat_bias(const float* __restrict__ bq, const float* __restrict__ bk,
                            const float* __restrict__ bv, float* __restrict__ dst) {
  const int z = blockIdx.x;
  const float* src = (z == 0) ? bq : (z == 1) ? bk : bv;
  const int i = threadIdx.x;
  ((float4*)(dst + z * 1024))[i] = ((const float4*)src)[i];
}

// One block per row of 2048 bf16 scores; softmax in fp32, bf16 in place.
__global__ __launch_bounds__(256) void softmax_bf16(unsigned short* __restrict__ scores) {
  unsigned short* p = scores + (size_t)blockIdx.x * 2048;
  const int t = threadIdx.x;
  uint4 raw = ((const uint4*)p)[t];
  float v[8];
  v[0] = __uint_as_float(raw.x << 16); v[1] = __uint_as_float(raw.x & 0xffff0000u);
  v[2] = __uint_as_float(raw.y << 16); v[3] = __uint_as_float(raw.y & 0xffff0000u);
  v[4] = __uint_as_float(raw.z << 16); v[5] = __uint_as_float(raw.z & 0xffff0000u);
  v[6] = __uint_as_float(raw.w << 16); v[7] = __uint_as_float(raw.w & 0xffff0000u);

  float m = v[0];
#pragma unroll
  for (int i = 1; i < 8; ++i) m = fmaxf(m, v[i]);
#pragma unroll
  for (int off = 32; off; off >>= 1) m = fmaxf(m, __shfl_xor(m, off, 64));

  __shared__ float red[4];
  __shared__ float bcast[2];
  const int wave = t >> 6, lane = t & 63;
  if (lane == 0) red[wave] = m;
  __syncthreads();
  if (t == 0) bcast[0] = fmaxf(fmaxf(red[0], red[1]), fmaxf(red[2], red[3]));
  __syncthreads();
  m = bcast[0];

  float s = 0.f;
#pragma unroll
  for (int i = 0; i < 8; ++i) { v[i] = __expf(v[i] - m); s += v[i]; }
#pragma unroll
  for (int off = 32; off; off >>= 1) s += __shfl_xor(s, off, 64);
  if (lane == 0) red[wave] = s;
  __syncthreads();
  if (t == 0) bcast[1] = red[0] + red[1] + red[2] + red[3];
  __syncthreads();
  const float inv = 1.0f / bcast[1];

  uint4 ov;
  ov.x = (unsigned)f2bf(v[0] * inv) | ((unsigned)f2bf(v[1] * inv) << 16);
  ov.y = (unsigned)f2bf(v[2] * inv) | ((unsigned)f2bf(v[3] * inv) << 16);
  ov.z = (unsigned)f2bf(v[4] * inv) | ((unsigned)f2bf(v[5] * inv) << 16);
  ov.w = (unsigned)f2bf(v[6] * inv) | ((unsigned)f2bf(v[7] * inv) << 16);
  ((uint4*)p)[t] = ov;
}

// ---------------------------------------------------------------------------
extern "C" void kernel_launch(void* const* d_in, const int* in_sizes, int n_in,
                              void* d_out, int out_size, void* d_ws, size_t ws_size,
                              hipStream_t stream) {
  const float* x  = (const float*)d_in[0];
  const float* Wq = (const float*)d_in[1];
  const float* bq = (const float*)d_in[2];
  const float* Wk = (const float*)d_in[3];
  const float* bk = (const float*)d_in[4];
  const float* Wv = (const float*)d_in[5];
  const float* bv = (const float*)d_in[6];
  const float* Wo = (const float*)d_in[7];
  const float* bo = (const float*)d_in[8];
  float* out = (float*)d_out;

  char* ws = (char*)d_ws;
  size_t off = 0;
  auto alloc = [&](size_t bytes) { char* p = ws + off; off += (bytes + 255) & ~255UL; return p; };
  unsigned short* xb    = (unsigned short*)alloc(8192UL * 1024 * 2);     // 16 MiB
  unsigned short* Wqkvb = (unsigned short*)alloc(3072UL * 1024 * 2);     // 6 MiB
  unsigned short* Wob   = (unsigned short*)alloc(1024UL * 1024 * 2);     // 2 MiB
  float*          bqkv  = (float*)alloc(3072UL * 4);
  unsigned short* Qb    = (unsigned short*)alloc(8192UL * 1024 * 2);     // 16 MiB (piece 0)
  unsigned short* Kb    = (unsigned short*)alloc(8192UL * 1024 * 2);     // 16 MiB (piece 1, == Qb + sC)
  unsigned short* Vtb   = (unsigned short*)alloc(4UL * 1024 * 2048 * 2); // 16 MiB [b][d][s]
  unsigned short* attn  = (unsigned short*)alloc(8192UL * 2048 * 2);     // 32 MiB bf16 scores
  unsigned short* ctxb  = (unsigned short*)alloc(8192UL * 1024 * 2);     // 16 MiB

  const dim3 blk(512);

  // input convert + all weight transposes + bias concat
  cvt_x<<<2097152 / 256, 256, 0, stream>>>(x, xb, 2097152);
  cvtT_w4<<<dim3(16, 16, 4), dim3(64, 4), 0, stream>>>(Wq, Wk, Wv, Wo, Wqkvb, Wob);
  concat_bias<<<3, 256, 0, stream>>>(bq, bk, bv, bqkv);

  // fused QKV projection: Q,K compact + V transposed to Vtb.
  gemm8p<unsigned short, true, 1><<<dim3(32, 12, 1), blk, 0, stream>>>(
      xb, Wqkvb, Qb, Vtb, bqkv, 1024, 1024, 1024, 1024, 0, 0, 8192L * 1024, 1.0f);

  // scores = (Q @ K^T) / 32 -> bf16, per batch
  gemm8p<unsigned short, false, 0><<<dim3(8, 8, 4), blk, 0, stream>>>(
      Qb, Kb, attn, nullptr, nullptr, 1024, 1024, 1024, 2048,
      2048L * 1024, 2048L * 1024, 2048L * 2048, 0.03125f);

  // softmax rows in place (bf16, dense ld=2048)
  softmax_bf16<<<8192, 256, 0, stream>>>(attn);

  // ctx = attn @ V  (attn lda=2048, Vt is Bt layout)
  gemm8p<unsigned short, false, 0><<<dim3(8, 4, 4), blk, 0, stream>>>(
      attn, Vtb, ctxb, nullptr, nullptr, 2048, 2048, 2048, 1024,
      2048L * 2048, 1024L * 2048, 2048L * 1024, 1.0f);

  // out = ctx @ Wo + bo (fp32 out)
  gemm8p<float, true, 0><<<dim3(32, 4, 1), blk, 0, stream>>>(
      ctxb, Wob, out, nullptr, bo, 1024, 1024, 1024, 1024, 0, 0, 0, 1.0f);
}

// Round 4
// 298.236 us; speedup vs baseline: 1.1011x; 1.0843x over previous
//
#include <hip/hip_runtime.h>

typedef __attribute__((ext_vector_type(8))) short bf16x8;
typedef __attribute__((ext_vector_type(4))) float f32x4;
typedef __attribute__((ext_vector_type(4))) unsigned short us4;

#define AS1 __attribute__((address_space(1)))
#define AS3 __attribute__((address_space(3)))

__device__ __forceinline__ unsigned short f2bf(float f) {
  unsigned u = __float_as_uint(f);
  u += 0x7fff + ((u >> 16) & 1);   // RNE
  return (unsigned short)(u >> 16);
}

__device__ __forceinline__ void gload_lds16(const void* g, void* l) {
  __builtin_amdgcn_global_load_lds((const AS1 unsigned int*)g,
                                   (AS3 unsigned int*)l, 16, 0, 0);
}

#define MFMA16(a, b, c) __builtin_amdgcn_mfma_f32_16x16x32_bf16(a, b, c, 0, 0, 0)

// ---------------------------------------------------------------------------
// BM=256 x BN=128, BK=32 bf16 GEMM, one window per K-tile, 3-deep LDS ring.
// C[M,N] = scale*(A[M,K] @ Bt[N,K]^T) + bias.
// 512 thr = 8 waves: wm = wave>>1 (0..3), wn = wave&1 (0..1); per-wave 64x64
// = acc[4][4] of 16x16x32 MFMA (16 independent MFMA per window).
// LDS: ring of 3 buffers, each A[256][32] + B[128][32] bf16 = 24 KB (72 KB).
// 32-B rows => every fragment read (16 rows x 4 chunks) is a bijection onto
// a contiguous 1 KB block: ZERO bank conflicts with NO swizzle. Stage calls
// are linear (dest = wave-uniform base + lane*16B, required by
// global_load_lds); 3 calls per tile: A rows 0-127, A rows 128-255, B 0-127.
// Window t: stage(t+2) [3 gloads, earliest issue] ; ds_read af[4],b[4] of
// tile t ; 16 MFMA ; vmcnt(3) ; s_barrier.
//   vmcnt proof (steady state): at window end, outstanding = g(t+1)[3] +
//   g(t+2)[3] = 6 -> vmcnt(3) drains exactly g(t+1), one full window before
//   its reads in window t+1; per-wave vmcnt + barrier => unit complete
//   CU-wide (each wave stages slices of every call in identical order).
//   Tail: t==NT-2 -> vmcnt(0) (only 3 outstanding); t==NT-1 -> no wait.
// WAR: stage(t+2) overwrites buf[(t-1)%3]; its reads completed (lgkm-drained
// before window t-1's MFMA) and the end-of-window barrier was crossed.
// MODE 0: C[bz*sC + row*ldc + col]. MODE 1 (fused QKV): piece = col0>>10
//   (wave-uniform, 64-col wave span); pieces 0,1 -> compact [8192][1024] at
//   C + piece*sC; piece 2 -> V transposed to Vt[b][d][2048], b=blockIdx.x>>3.
// ---------------------------------------------------------------------------
template <typename OutT, bool BIAS, int MODE>
__global__ __launch_bounds__(512, 2) void gemmk(
    const unsigned short* __restrict__ A,
    const unsigned short* __restrict__ Bt,
    OutT* __restrict__ C,
    unsigned short* __restrict__ Vt,
    const float* __restrict__ bias,
    int Kd, int lda, int ldb, int ldc,
    long sA, long sB, long sC,
    float scale) {
  constexpr int ABUF  = 256 * 32;          // ushorts
  constexpr int BUFSZ = ABUF + 128 * 32;   // 12288 ushorts = 24 KB
  __shared__ unsigned short lds[3 * BUFSZ];

  const int bz = blockIdx.z;
  A  += (size_t)bz * sA + (size_t)blockIdx.x * 256 * lda;
  Bt += (size_t)bz * sB + (size_t)blockIdx.y * 128 * ldb;

  const int tid  = threadIdx.x;
  const int wave = tid >> 6;
  const int lane = tid & 63;
  const int wm   = wave >> 1;              // 0..3
  const int wn   = wave & 1;               // 0..1
  const int l15  = lane & 15;
  const int hi   = lane >> 4;              // 0..3
  // stage: each call covers 128 rows x 32 cols; thread row = tid>>2,
  // chunk = tid&3; LDS offset = tid*8 ushorts = wave*512 + lane*8 (linear).
  const int srow = tid >> 2;               // 0..127
  const int schk = (tid & 3) * 8;          // ushort offset in row

  auto stage = [&](int bi, int k0) {
    unsigned short* L = &lds[bi * BUFSZ + wave * 512];   // wave-uniform dest
    const unsigned short* ga = A + (size_t)srow * lda + (k0 + schk);
    gload_lds16(ga, L);                                   // A rows 0-127
    gload_lds16(ga + (size_t)128 * lda, L + 4096);        // A rows 128-255
    gload_lds16(Bt + (size_t)srow * ldb + (k0 + schk), L + 8192);  // B 0-127
  };

  f32x4 acc[4][4] = {};

  // prologue: stage tiles 0 and 1, drain tile 0 (keep tile 1 in flight)
  stage(0, 0);
  stage(1, 32);
  asm volatile("s_waitcnt vmcnt(3)" ::: "memory");
  __builtin_amdgcn_s_barrier();

  const int NT = Kd >> 5;
  int bufi = 0;
  const int rdA = (wm * 64 + l15) * 32 + hi * 8;          // af[0] offset
  const int rdB = ABUF + (wn * 64 + l15) * 32 + hi * 8;   // b[0] offset
  for (int t = 0; t < NT; ++t) {
    if (t + 2 < NT) {
      int nbi = bufi + 2; if (nbi >= 3) nbi -= 3;
      stage(nbi, (t + 2) << 5);
    }
    const unsigned short* L = &lds[bufi * BUFSZ];
    bf16x8 af[4], bf[4];
#pragma unroll
    for (int mt = 0; mt < 4; ++mt)
      af[mt] = *(const bf16x8*)&L[rdA + mt * 16 * 32];
#pragma unroll
    for (int nt = 0; nt < 4; ++nt)
      bf[nt] = *(const bf16x8*)&L[rdB + nt * 16 * 32];
    __builtin_amdgcn_s_setprio(1);
#pragma unroll
    for (int mt = 0; mt < 4; ++mt)
#pragma unroll
      for (int nt = 0; nt < 4; ++nt)
        acc[mt][nt] = MFMA16(af[mt], bf[nt], acc[mt][nt]);
    __builtin_amdgcn_s_setprio(0);
    if (t + 2 < NT)      asm volatile("s_waitcnt vmcnt(3)" ::: "memory");
    else if (t + 1 < NT) asm volatile("s_waitcnt vmcnt(0)" ::: "memory");
    __builtin_amdgcn_s_barrier();
    bufi = (bufi + 1 == 3) ? 0 : bufi + 1;
  }

  // ------------------------------- epilogue -------------------------------
  const int hi4  = hi << 2;
  const int row0 = blockIdx.x * 256 + wm * 64;
  const int col0 = blockIdx.y * 128 + wn * 64;

  if constexpr (MODE == 1) {
    const int piece = col0 >> 10;                 // wave-uniform
    float bvv[4];
#pragma unroll
    for (int nt = 0; nt < 4; ++nt)
      bvv[nt] = BIAS ? bias[col0 + nt * 16 + l15] : 0.0f;
    if (piece < 2) {
      OutT* dst = C + (size_t)piece * sC;
      const int cb = (col0 & 1023) + l15;
#pragma unroll
      for (int mt = 0; mt < 4; ++mt)
#pragma unroll
        for (int r = 0; r < 4; ++r) {
          const size_t rowoff = (size_t)(row0 + mt * 16 + hi4 + r) * ldc;
#pragma unroll
          for (int nt = 0; nt < 4; ++nt)
            dst[rowoff + cb + nt * 16] = (OutT)f2bf(acc[mt][nt][r] * scale + bvv[nt]);
        }
    } else {
      // V piece: write transposed Vt[b][d][2048]
      const int b = blockIdx.x >> 3;
      const int sb = (blockIdx.x & 7) * 256 + wm * 64 + hi4;
#pragma unroll
      for (int nt = 0; nt < 4; ++nt) {
        const int d = ((col0 + nt * 16) & 1023) + l15;
#pragma unroll
        for (int mt = 0; mt < 4; ++mt) {
          us4 pk;
          pk.x = f2bf(acc[mt][nt][0] * scale + bvv[nt]);
          pk.y = f2bf(acc[mt][nt][1] * scale + bvv[nt]);
          pk.z = f2bf(acc[mt][nt][2] * scale + bvv[nt]);
          pk.w = f2bf(acc[mt][nt][3] * scale + bvv[nt]);
          *(us4*)&Vt[((size_t)b << 21) + (size_t)d * 2048 + sb + mt * 16] = pk;
        }
      }
    }
  } else {
    C += (size_t)bz * sC;
    float bvv[4];
#pragma unroll
    for (int nt = 0; nt < 4; ++nt)
      bvv[nt] = BIAS ? bias[col0 + nt * 16 + l15] : 0.0f;
    const int cb = col0 + l15;
#pragma unroll
    for (int mt = 0; mt < 4; ++mt)
#pragma unroll
      for (int r = 0; r < 4; ++r) {
        const size_t rowoff = (size_t)(row0 + mt * 16 + hi4 + r) * ldc;
#pragma unroll
        for (int nt = 0; nt < 4; ++nt) {
          const float v = acc[mt][nt][r] * scale + bvv[nt];
          if constexpr (sizeof(OutT) == 4)
            C[rowoff + cb + nt * 16] = v;
          else
            C[rowoff + cb + nt * 16] = (OutT)f2bf(v);
        }
      }
  }
}

// fp32 -> bf16 flat convert (4 elems/thread)
__global__ void cvt_x(const float* __restrict__ in, unsigned short* __restrict__ out, int n4) {
  const int i = blockIdx.x * blockDim.x + threadIdx.x;
  if (i < n4) {
    const float4 v = ((const float4*)in)[i];
    uint2 o;
    o.x = (unsigned)f2bf(v.x) | ((unsigned)f2bf(v.y) << 16);
    o.y = (unsigned)f2bf(v.z) | ((unsigned)f2bf(v.w) << 16);
    ((uint2*)out)[i] = o;
  }
}

// All 4 weight matrices (1024x1024 fp32) -> bf16 transposed, one launch.
__global__ void cvtT_w4(const float* __restrict__ Wq, const float* __restrict__ Wk,
                        const float* __restrict__ Wv, const float* __restrict__ Wo,
                        unsigned short* __restrict__ Wqkvb, unsigned short* __restrict__ Wob) {
  __shared__ unsigned short tile[64][65];
  const int z = blockIdx.z;
  const float* in = (z == 0) ? Wq : (z == 1) ? Wk : (z == 2) ? Wv : Wo;
  unsigned short* out = (z == 3) ? Wob : Wqkvb + (size_t)z * 1024 * 1024;
  const int r0 = blockIdx.y * 64, c0 = blockIdx.x * 64;
  for (int i = threadIdx.y; i < 64; i += 4)
    tile[i][threadIdx.x] = f2bf(in[(size_t)(r0 + i) * 1024 + c0 + threadIdx.x]);
  __syncthreads();
  for (int i = threadIdx.y; i < 64; i += 4)
    out[(size_t)(c0 + i) * 1024 + r0 + threadIdx.x] = tile[threadIdx.x][i];
}

// concat bq|bk|bv into bqkv
__global__ void concat_bias(const float* __restrict__ bq, const float* __restrict__ bk,
                            const float* __restrict__ bv, float* __restrict__ dst) {
  const int z = blockIdx.x;
  const float* src = (z == 0) ? bq : (z == 1) ? bk : bv;
  const int i = threadIdx.x;
  ((float4*)(dst + z * 1024))[i] = ((const float4*)src)[i];
}

// One block per row of 2048 bf16 scores; softmax in fp32, bf16 in place.
__global__ __launch_bounds__(256) void softmax_bf16(unsigned short* __restrict__ scores) {
  unsigned short* p = scores + (size_t)blockIdx.x * 2048;
  const int t = threadIdx.x;
  uint4 raw = ((const uint4*)p)[t];
  float v[8];
  v[0] = __uint_as_float(raw.x << 16); v[1] = __uint_as_float(raw.x & 0xffff0000u);
  v[2] = __uint_as_float(raw.y << 16); v[3] = __uint_as_float(raw.y & 0xffff0000u);
  v[4] = __uint_as_float(raw.z << 16); v[5] = __uint_as_float(raw.z & 0xffff0000u);
  v[6] = __uint_as_float(raw.w << 16); v[7] = __uint_as_float(raw.w & 0xffff0000u);

  float m = v[0];
#pragma unroll
  for (int i = 1; i < 8; ++i) m = fmaxf(m, v[i]);
#pragma unroll
  for (int off = 32; off; off >>= 1) m = fmaxf(m, __shfl_xor(m, off, 64));

  __shared__ float red[4];
  __shared__ float bcast[2];
  const int wave = t >> 6, lane = t & 63;
  if (lane == 0) red[wave] = m;
  __syncthreads();
  if (t == 0) bcast[0] = fmaxf(fmaxf(red[0], red[1]), fmaxf(red[2], red[3]));
  __syncthreads();
  m = bcast[0];

  float s = 0.f;
#pragma unroll
  for (int i = 0; i < 8; ++i) { v[i] = __expf(v[i] - m); s += v[i]; }
#pragma unroll
  for (int off = 32; off; off >>= 1) s += __shfl_xor(s, off, 64);
  if (lane == 0) red[wave] = s;
  __syncthreads();
  if (t == 0) bcast[1] = red[0] + red[1] + red[2] + red[3];
  __syncthreads();
  const float inv = 1.0f / bcast[1];

  uint4 ov;
  ov.x = (unsigned)f2bf(v[0] * inv) | ((unsigned)f2bf(v[1] * inv) << 16);
  ov.y = (unsigned)f2bf(v[2] * inv) | ((unsigned)f2bf(v[3] * inv) << 16);
  ov.z = (unsigned)f2bf(v[4] * inv) | ((unsigned)f2bf(v[5] * inv) << 16);
  ov.w = (unsigned)f2bf(v[6] * inv) | ((unsigned)f2bf(v[7] * inv) << 16);
  ((uint4*)p)[t] = ov;
}

// ---------------------------------------------------------------------------
extern "C" void kernel_launch(void* const* d_in, const int* in_sizes, int n_in,
                              void* d_out, int out_size, void* d_ws, size_t ws_size,
                              hipStream_t stream) {
  const float* x  = (const float*)d_in[0];
  const float* Wq = (const float*)d_in[1];
  const float* bq = (const float*)d_in[2];
  const float* Wk = (const float*)d_in[3];
  const float* bk = (const float*)d_in[4];
  const float* Wv = (const float*)d_in[5];
  const float* bv = (const float*)d_in[6];
  const float* Wo = (const float*)d_in[7];
  const float* bo = (const float*)d_in[8];
  float* out = (float*)d_out;

  char* ws = (char*)d_ws;
  size_t off = 0;
  auto alloc = [&](size_t bytes) { char* p = ws + off; off += (bytes + 255) & ~255UL; return p; };
  unsigned short* xb    = (unsigned short*)alloc(8192UL * 1024 * 2);     // 16 MiB
  unsigned short* Wqkvb = (unsigned short*)alloc(3072UL * 1024 * 2);     // 6 MiB
  unsigned short* Wob   = (unsigned short*)alloc(1024UL * 1024 * 2);     // 2 MiB
  float*          bqkv  = (float*)alloc(3072UL * 4);
  unsigned short* Qb    = (unsigned short*)alloc(8192UL * 1024 * 2);     // 16 MiB (piece 0)
  unsigned short* Kb    = (unsigned short*)alloc(8192UL * 1024 * 2);     // 16 MiB (piece 1, == Qb + sC)
  unsigned short* Vtb   = (unsigned short*)alloc(4UL * 1024 * 2048 * 2); // 16 MiB [b][d][s]
  unsigned short* attn  = (unsigned short*)alloc(8192UL * 2048 * 2);     // 32 MiB bf16 scores
  unsigned short* ctxb  = (unsigned short*)alloc(8192UL * 1024 * 2);     // 16 MiB

  const dim3 blk(512);

  // input convert + all weight transposes + bias concat
  cvt_x<<<2097152 / 256, 256, 0, stream>>>(x, xb, 2097152);
  cvtT_w4<<<dim3(16, 16, 4), dim3(64, 4), 0, stream>>>(Wq, Wk, Wv, Wo, Wqkvb, Wob);
  concat_bias<<<3, 256, 0, stream>>>(bq, bk, bv, bqkv);

  // fused QKV projection: Q,K compact + V transposed to Vtb. 768 blocks.
  gemmk<unsigned short, true, 1><<<dim3(32, 24, 1), blk, 0, stream>>>(
      xb, Wqkvb, Qb, Vtb, bqkv, 1024, 1024, 1024, 1024, 0, 0, 8192L * 1024, 1.0f);

  // scores = (Q @ K^T) / 32 -> bf16, per batch. 512 blocks.
  gemmk<unsigned short, false, 0><<<dim3(8, 16, 4), blk, 0, stream>>>(
      Qb, Kb, attn, nullptr, nullptr, 1024, 1024, 1024, 2048,
      2048L * 1024, 2048L * 1024, 2048L * 2048, 0.03125f);

  // softmax rows in place (bf16, dense ld=2048)
  softmax_bf16<<<8192, 256, 0, stream>>>(attn);

  // ctx = attn @ V  (attn lda=2048, Vt is Bt layout). 256 blocks.
  gemmk<unsigned short, false, 0><<<dim3(8, 8, 4), blk, 0, stream>>>(
      attn, Vtb, ctxb, nullptr, nullptr, 2048, 2048, 2048, 1024,
      2048L * 2048, 1024L * 2048, 2048L * 1024, 1.0f);

  // out = ctx @ Wo + bo (fp32 out). 256 blocks.
  gemmk<float, true, 0><<<dim3(32, 8, 1), blk, 0, stream>>>(
      ctxb, Wob, out, nullptr, bo, 1024, 1024, 1024, 1024, 0, 0, 0, 1.0f);
}